// Round 3
// baseline (662.003 us; speedup 1.0000x reference)
//
#include <hip/hip_runtime.h>
#include <hip/hip_bf16.h>

typedef __attribute__((ext_vector_type(8))) short short8;   // 8 bf16 = 4 VGPRs (MFMA A/B frag)
typedef __attribute__((ext_vector_type(4))) float floatx4;  // MFMA C/D frag

#define NB 8
#define NN 2048
#define DD 512

__device__ __forceinline__ unsigned short f2bf(float f) {
  union { float f; unsigned int u; } v; v.f = f;
  unsigned int u = v.u;
  return (unsigned short)((u + 0x7fffu + ((u >> 16) & 1u)) >> 16);  // RNE
}
__device__ __forceinline__ float bf2f(unsigned short s) {
  union { unsigned int u; float f; } v; v.u = ((unsigned int)s) << 16;
  return v.f;
}

typedef __attribute__((address_space(3))) unsigned short lds_us;
typedef __attribute__((address_space(1))) const unsigned short glb_us;

__device__ __forceinline__ void ld_lds16(const unsigned short* g, unsigned short* l) {
  // async global->LDS DMA, 16 B per lane; LDS dest is wave-uniform base + lane*16
  __builtin_amdgcn_global_load_lds((glb_us*)g, (lds_us*)l, 16, 0, 0);
}

// ---- elementwise convert H (fp32) -> bf16, 8 elems/thread ----
__global__ __launch_bounds__(256) void mha_cvtH(const float* __restrict__ H,
                                                unsigned short* __restrict__ Hb, int n8) {
  int i = blockIdx.x * 256 + threadIdx.x;
  if (i >= n8) return;
  const float4* src = (const float4*)H;
  float4 a = src[2 * i], b = src[2 * i + 1];
  short8 o;
  o[0] = (short)f2bf(a.x); o[1] = (short)f2bf(a.y); o[2] = (short)f2bf(a.z); o[3] = (short)f2bf(a.w);
  o[4] = (short)f2bf(b.x); o[5] = (short)f2bf(b.y); o[6] = (short)f2bf(b.z); o[7] = (short)f2bf(b.w);
  *(short8*)(Hb + 8 * i) = o;
}

// ---- transpose-convert W [k][d] fp32 -> Wt [d][k] bf16 (32x32 tiles) ----
__global__ __launch_bounds__(256) void mha_tW(const float* __restrict__ Wq, const float* __restrict__ Wk,
                                              const float* __restrict__ Wv,
                                              unsigned short* __restrict__ Wqt, unsigned short* __restrict__ Wkt,
                                              unsigned short* __restrict__ Wvt) {
  const float* W = (blockIdx.z == 0) ? Wq : (blockIdx.z == 1) ? Wk : Wv;
  unsigned short* Wt = (blockIdx.z == 0) ? Wqt : (blockIdx.z == 1) ? Wkt : Wvt;
  __shared__ float tile[32][33];
  int d0 = blockIdx.x * 32, k0 = blockIdx.y * 32;
  int t = threadIdx.x, r = t >> 3, c4 = (t & 7) * 4;
  float4 v = *(const float4*)(W + (size_t)(k0 + r) * DD + d0 + c4);
  tile[r][c4] = v.x; tile[r][c4 + 1] = v.y; tile[r][c4 + 2] = v.z; tile[r][c4 + 3] = v.w;
  __syncthreads();
  union { unsigned short s[4]; uint2 v; } u;
  u.s[0] = f2bf(tile[c4][r]);     u.s[1] = f2bf(tile[c4 + 1][r]);
  u.s[2] = f2bf(tile[c4 + 2][r]); u.s[3] = f2bf(tile[c4 + 3][r]);
  *(uint2*)(Wt + (size_t)(d0 + r) * DD + k0 + c4) = u.v;
}

// ---- transpose V (bf16) [b][n][d] -> Vt [b][d][n] (32x32 tiles) ----
__global__ __launch_bounds__(256) void mha_tV(const unsigned short* __restrict__ Vr,
                                              unsigned short* __restrict__ Vt) {
  int b = blockIdx.z;
  int d0 = blockIdx.x * 32, n0 = blockIdx.y * 32;
  __shared__ unsigned short tile[32][34];
  int t = threadIdx.x, r = t >> 3, c4 = (t & 7) * 4;
  union { uint2 v; unsigned short s[4]; } u;
  u.v = *(const uint2*)(Vr + ((size_t)b * NN + n0 + r) * DD + d0 + c4);
  tile[r][c4] = u.s[0]; tile[r][c4 + 1] = u.s[1]; tile[r][c4 + 2] = u.s[2]; tile[r][c4 + 3] = u.s[3];
  __syncthreads();
  union { unsigned short s[4]; uint2 v; } o;
  o.s[0] = tile[c4][r]; o.s[1] = tile[c4 + 1][r]; o.s[2] = tile[c4 + 2][r]; o.s[3] = tile[c4 + 3][r];
  *(uint2*)(Vt + ((size_t)b * DD + d0 + r) * NN + n0 + c4) = o.v;
}

// ---- GEMM staging: rows x 32-k slices, seg-swizzled so global_load_lds (no pad) is conflict-free ----
// logical k-chunk l of row r stored at physical chunk (l + (r>>1)) & 3 within the row's 4x16B.

__device__ __forceinline__ void stage_tile_async(const unsigned short* __restrict__ g, int ld,
                                                 unsigned short* s, int t) {
#pragma unroll
  for (int h = 0; h < 2; ++h) {
    int c = t + h * 256;            // chunk 0..511 (128 rows x 4 chunks)
    int r = c >> 2, p = c & 3;
    int seg = (p - (r >> 1)) & 3;
    ld_lds16(g + (size_t)r * ld + seg * 8, s + c * 8);
  }
}

__device__ __forceinline__ void mfma_step(const unsigned short* As, const unsigned short* Bs,
                                          int wr, int wc, int quad, int lr, floatx4 acc[4][4]) {
  short8 a[4], b[4];
#pragma unroll
  for (int i = 0; i < 4; ++i) {
    int ra = wr * 64 + i * 16 + lr;
    int rb = wc * 64 + i * 16 + lr;
    a[i] = *(const short8*)(As + ra * 32 + ((quad + (ra >> 1)) & 3) * 8);
    b[i] = *(const short8*)(Bs + rb * 32 + ((quad + (rb >> 1)) & 3) * 8);
  }
#pragma unroll
  for (int i = 0; i < 4; ++i)
#pragma unroll
    for (int j = 0; j < 4; ++j)
      acc[i][j] = __builtin_amdgcn_mfma_f32_16x16x32_bf16(a[i], b[j], acc[i][j], 0, 0, 0);
}

// ---- QKV projection: C[m][d] = sum_k Hb[m][k] * Wt[d][k], bf16 out ----
__global__ __launch_bounds__(256) void mha_proj(const unsigned short* __restrict__ Hb,
                                                const unsigned short* __restrict__ Wqt,
                                                const unsigned short* __restrict__ Wkt,
                                                const unsigned short* __restrict__ Wvt,
                                                unsigned short* __restrict__ Qb,
                                                unsigned short* __restrict__ Kb,
                                                unsigned short* __restrict__ Vr) {
  const unsigned short* Wt = (blockIdx.z == 0) ? Wqt : (blockIdx.z == 1) ? Wkt : Wvt;
  unsigned short* dst = (blockIdx.z == 0) ? Qb : (blockIdx.z == 1) ? Kb : Vr;
  __shared__ unsigned short As[128 * 32], Bs[128 * 32];
  int t = threadIdx.x, wave = t >> 6, lane = t & 63, quad = lane >> 4, lr = lane & 15;
  int wr = wave >> 1, wc = wave & 1;
  int m0 = blockIdx.y * 128, n0 = blockIdx.x * 128;
  floatx4 acc[4][4] = {};
  for (int k0 = 0; k0 < DD; k0 += 32) {
    __syncthreads();
    stage_tile_async(Hb + (size_t)m0 * DD + k0, DD, As, t);
    stage_tile_async(Wt + (size_t)n0 * DD + k0, DD, Bs, t);
    __syncthreads();
    mfma_step(As, Bs, wr, wc, quad, lr, acc);
  }
#pragma unroll
  for (int i = 0; i < 4; ++i)
#pragma unroll
    for (int j = 0; j < 4; ++j)
#pragma unroll
      for (int r = 0; r < 4; ++r) {
        int row = m0 + wr * 64 + i * 16 + quad * 4 + r;
        int col = n0 + wc * 64 + j * 16 + lr;
        dst[(size_t)row * DD + col] = f2bf(acc[i][j][r]);
      }
}

// ---- fused attention: per block = 32 Q-rows, full key loop, O accumulated in regs ----
// LDS (exactly 80KB => 2 blocks/CU): Qs 8K | Ks 32K | Ps 8K | Vs 32K
// Fixed-shift softmax: e = exp(scale*s + bias - 16), masked -> 0; no running max needed.
__global__ __launch_bounds__(256, 2) void mha_fused(const unsigned short* __restrict__ Qb,
                                                    const unsigned short* __restrict__ Kb,
                                                    const unsigned short* __restrict__ Vt,
                                                    const float* __restrict__ bias,
                                                    const int* __restrict__ mask,
                                                    float* __restrict__ out) {
  __shared__ unsigned short smem[40960];          // 80 KB
  unsigned short* Qs = smem;                       // 4096 elems: 4 slices x (32r x 32k)
  unsigned short* Ks = smem + 4096;                // 16384: 4 slices x (128r x 32k)
  unsigned short* Ps = smem + 20480;               // 4096: 4 j-slices x (32r x 32j)
  unsigned short* Vs = smem + 24576;               // 16384: 512r x 32j
  float* ls = (float*)smem;                        // 32 floats, reuses Qs after j-loop

  int b = blockIdx.x;                              // batch in XCD round-robin position
  int i0 = blockIdx.y * 32;
  int t = threadIdx.x, wave = t >> 6, lane = t & 63, quad = lane >> 4, lr = lane & 15;
  const unsigned short* Qg = Qb + ((size_t)b * NN + i0) * DD;
  const unsigned short* Kg = Kb + (size_t)b * NN * DD;
  const unsigned short* Vg = Vt + (size_t)b * DD * NN;
  const float scale = 0.04419417382415922f;        // 1/sqrt(512)

  floatx4 acc[2][8] = {};                          // O: 2 row-tiles x 8 col-tiles (wave's 128 c-cols)
  float rs[2][4] = {};                             // row-sum partials

  for (int jt = 0; jt < 16; ++jt) {
    int j0 = jt * 128;
    floatx4 sacc[2][2] = {};                       // S: 2 row-tiles x 2 col-tiles (wave's 32 j-cols)

    // ---- QK^T over K=512 in 4 stages of 128 ----
    for (int k0 = 0; k0 < DD; k0 += 128) {
      __syncthreads();
#pragma unroll
      for (int h = 0; h < 2; ++h) {                // Qs: 512 chunks
        int d = t + h * 256;
        int s = d >> 7, w = d & 127, r = w >> 2, p = w & 3;
        int l = (p - (r >> 1)) & 3;
        ld_lds16(Qg + (size_t)r * DD + k0 + (s * 4 + l) * 8, Qs + d * 8);
      }
#pragma unroll
      for (int h = 0; h < 8; ++h) {                // Ks: 2048 chunks
        int d = t + h * 256;
        int s = d >> 9, w = d & 511, r = w >> 2, p = w & 3;
        int l = (p - (r >> 1)) & 3;
        ld_lds16(Kg + (size_t)(j0 + r) * DD + k0 + (s * 4 + l) * 8, Ks + d * 8);
      }
      __syncthreads();
#pragma unroll
      for (int ss = 0; ss < 4; ++ss) {
        short8 a[2], bb[2];
#pragma unroll
        for (int i = 0; i < 2; ++i) {
          int ra = i * 16 + lr;
          a[i] = *(const short8*)(Qs + ss * 1024 + ra * 32 + ((quad + (ra >> 1)) & 3) * 8);
        }
#pragma unroll
        for (int j = 0; j < 2; ++j) {
          int rb = wave * 32 + j * 16 + lr;
          bb[j] = *(const short8*)(Ks + ss * 4096 + rb * 32 + ((quad + (rb >> 1)) & 3) * 8);
        }
#pragma unroll
        for (int i = 0; i < 2; ++i)
#pragma unroll
          for (int j = 0; j < 2; ++j)
            sacc[i][j] = __builtin_amdgcn_mfma_f32_16x16x32_bf16(a[i], bb[j], sacc[i][j], 0, 0, 0);
      }
    }

    // ---- S -> P (exp) into LDS; prev PV reads of Ps finished before this jt's first barrier ----
#pragma unroll
    for (int i = 0; i < 2; ++i)
#pragma unroll
      for (int jj = 0; jj < 2; ++jj)
#pragma unroll
        for (int rr = 0; rr < 4; ++rr) {
          int row_l = i * 16 + quad * 4 + rr;
          int jloc = jj * 16 + lr;                 // 0..31 within this wave's j-slice
          size_t off = ((size_t)b * NN + i0 + row_l) * NN + (j0 + wave * 32 + jloc);
          float bi = __builtin_nontemporal_load(&bias[off]);
          int mk = __builtin_nontemporal_load(&mask[off]);
          float s = sacc[i][jj][rr] * scale + bi - 16.0f;
          float e = (mk != 0) ? __expf(s) : 0.0f;
          unsigned short eb = f2bf(e);
          // A-layout slice=wave, swizzled chunks; each wave writes only its own 2KB slice
          Ps[wave * 1024 + row_l * 32 + (((jloc >> 3) + (row_l >> 1)) & 3) * 8 + (jloc & 7)] = eb;
          rs[i][rr] += bf2f(eb);                   // sum the ROUNDED value so P-sum == l exactly
        }
    __syncthreads();                               // Ps visible to all waves

    // ---- PV: O += P(32x128) * V(128 keys x 512 c), j in 4 slices of 32 ----
    for (int jk = 0; jk < 4; ++jk) {
      if (jk) __syncthreads();                     // Vs reuse guard
#pragma unroll
      for (int h = 0; h < 8; ++h) {                // Vs: 2048 chunks (512 c-rows x 4)
        int d = t + h * 256;
        int r = d >> 2, p = d & 3;
        int l = (p - (r >> 1)) & 3;
        ld_lds16(Vg + (size_t)r * NN + j0 + jk * 32 + l * 8, Vs + d * 8);
      }
      __syncthreads();
      short8 a[2];
#pragma unroll
      for (int i = 0; i < 2; ++i) {
        int ra = i * 16 + lr;
        a[i] = *(const short8*)(Ps + jk * 1024 + ra * 32 + ((quad + (ra >> 1)) & 3) * 8);
      }
#pragma unroll
      for (int jc = 0; jc < 8; ++jc) {
        int rb = wave * 128 + jc * 16 + lr;
        short8 bv = *(const short8*)(Vs + rb * 32 + ((quad + (rb >> 1)) & 3) * 8);
        acc[0][jc] = __builtin_amdgcn_mfma_f32_16x16x32_bf16(a[0], bv, acc[0][jc], 0, 0, 0);
        acc[1][jc] = __builtin_amdgcn_mfma_f32_16x16x32_bf16(a[1], bv, acc[1][jc], 0, 0, 0);
      }
    }
  }

  // ---- row-sum reduction (ls aliases dead Qs) ----
  __syncthreads();
  if (t < 32) ls[t] = 0.0f;
  __syncthreads();
#pragma unroll
  for (int i = 0; i < 2; ++i)
#pragma unroll
    for (int rr = 0; rr < 4; ++rr) {
      float v = rs[i][rr];
      v += __shfl_xor(v, 1);
      v += __shfl_xor(v, 2);
      v += __shfl_xor(v, 4);
      v += __shfl_xor(v, 8);
      if (lr == 0) atomicAdd(&ls[i * 16 + quad * 4 + rr], v);
    }
  __syncthreads();

  // ---- normalize + store ----
#pragma unroll
  for (int i = 0; i < 2; ++i)
#pragma unroll
    for (int rr = 0; rr < 4; ++rr) {
      int row_l = i * 16 + quad * 4 + rr;
      float linv = 1.0f / ls[row_l];
      size_t rowoff = ((size_t)b * NN + i0 + row_l) * DD + wave * 128;
#pragma unroll
      for (int jc = 0; jc < 8; ++jc)
        __builtin_nontemporal_store(acc[i][jc][rr] * linv, &out[rowoff + jc * 16 + lr]);
    }
}

extern "C" void kernel_launch(void* const* d_in, const int* in_sizes, int n_in,
                              void* d_out, int out_size, void* d_ws, size_t ws_size,
                              hipStream_t stream) {
  const float* H = (const float*)d_in[0];
  const float* bias = (const float*)d_in[1];
  const int* mask = (const int*)d_in[2];
  const float* Wq = (const float*)d_in[3];
  const float* Wk = (const float*)d_in[4];
  const float* Wv = (const float*)d_in[5];
  float* out = (float*)d_out;
  char* ws = (char*)d_ws;

  const size_t SZ_QKV = (size_t)NB * NN * DD * 2;  // 16 MB (bf16)
  const size_t SZ_W = (size_t)DD * DD * 2;          // 512 KB
  unsigned short* Qb = (unsigned short*)(ws);
  unsigned short* Kb = (unsigned short*)(ws + SZ_QKV);
  unsigned short* Vt = (unsigned short*)(ws + 2 * SZ_QKV);
  unsigned short* Hb = (unsigned short*)(ws + 3 * SZ_QKV);
  unsigned short* Wqt = (unsigned short*)(ws + 4 * SZ_QKV);
  unsigned short* Wkt = (unsigned short*)(ws + 4 * SZ_QKV + SZ_W);
  unsigned short* Wvt = (unsigned short*)(ws + 4 * SZ_QKV + 2 * SZ_W);
  unsigned short* Vr = (unsigned short*)(ws + 4 * SZ_QKV + 3 * SZ_W);
  // total: 5*16MB + 1.5MB ~= 82 MB (< previously-working 115 MB)

  mha_cvtH<<<dim3((NB * NN * DD / 8) / 256), 256, 0, stream>>>(H, Hb, NB * NN * DD / 8);
  mha_tW<<<dim3(DD / 32, DD / 32, 3), 256, 0, stream>>>(Wq, Wk, Wv, Wqt, Wkt, Wvt);
  mha_proj<<<dim3(DD / 128, NB * NN / 128, 3), 256, 0, stream>>>(Hb, Wqt, Wkt, Wvt, Qb, Kb, Vr);
  mha_tV<<<dim3(DD / 32, NN / 32, NB), 256, 0, stream>>>(Vr, Vt);
  // grid: batch in x so XCD (= linear_id % 8) caches exactly one batch's K+V (4MB = one L2)
  mha_fused<<<dim3(NB, NN / 32), 256, 0, stream>>>(Qb, Kb, Vt, bias, mask, out);
}

// Round 5
// 494.037 us; speedup vs baseline: 1.3400x; 1.3400x over previous
//
#include <hip/hip_runtime.h>
#include <hip/hip_bf16.h>

typedef __attribute__((ext_vector_type(8))) short short8;   // 8 bf16 = 4 VGPRs (MFMA A/B frag)
typedef __attribute__((ext_vector_type(4))) float floatx4;  // MFMA C/D frag
typedef __attribute__((ext_vector_type(4))) int intx4;
typedef __attribute__((ext_vector_type(4))) unsigned short ushortx4;

#define NB 8
#define NN 2048
#define DD 512

__device__ __forceinline__ unsigned short f2bf(float f) {
  union { float f; unsigned int u; } v; v.f = f;
  unsigned int u = v.u;
  return (unsigned short)((u + 0x7fffu + ((u >> 16) & 1u)) >> 16);  // RNE
}
__device__ __forceinline__ float bf2f(unsigned short s) {
  union { unsigned int u; float f; } v; v.u = ((unsigned int)s) << 16;
  return v.f;
}

typedef __attribute__((address_space(3))) unsigned short lds_us;
typedef __attribute__((address_space(1))) const unsigned short glb_us;

__device__ __forceinline__ void ld_lds16(const unsigned short* g, unsigned short* l) {
  // async global->LDS DMA, 16 B per lane; LDS dest MUST be lane-linear (base + lane*16),
  // so all swizzling goes on the GLOBAL address side.
  __builtin_amdgcn_global_load_lds((glb_us*)g, (lds_us*)l, 16, 0, 0);
}

// ---- elementwise convert H (fp32) -> bf16, 8 elems/thread ----
__global__ __launch_bounds__(256) void mha_cvtH(const float* __restrict__ H,
                                                unsigned short* __restrict__ Hb, int n8) {
  int i = blockIdx.x * 256 + threadIdx.x;
  if (i >= n8) return;
  const float4* src = (const float4*)H;
  float4 a = src[2 * i], b = src[2 * i + 1];
  short8 o;
  o[0] = (short)f2bf(a.x); o[1] = (short)f2bf(a.y); o[2] = (short)f2bf(a.z); o[3] = (short)f2bf(a.w);
  o[4] = (short)f2bf(b.x); o[5] = (short)f2bf(b.y); o[6] = (short)f2bf(b.z); o[7] = (short)f2bf(b.w);
  *(short8*)(Hb + 8 * i) = o;
}

// ---- prep: bm = mask ? bf16(bias) : -inf   (268 MB -> 67 MB, pure streaming) ----
__global__ __launch_bounds__(256) void mha_prep(const floatx4* __restrict__ bias,
                                                const intx4* __restrict__ mask,
                                                ushortx4* __restrict__ bm) {
  int i = blockIdx.x * 256 + threadIdx.x;   // one 4-vector per thread
  floatx4 bv = __builtin_nontemporal_load(&bias[i]);
  intx4 mv = __builtin_nontemporal_load(&mask[i]);
  const unsigned short NINF = 0xFF80;       // bf16 -inf -> expf gives exact 0
  ushortx4 o;
  o.x = mv.x ? f2bf(bv.x) : NINF;
  o.y = mv.y ? f2bf(bv.y) : NINF;
  o.z = mv.z ? f2bf(bv.z) : NINF;
  o.w = mv.w ? f2bf(bv.w) : NINF;
  __builtin_nontemporal_store(o, &bm[i]);
}

// ---- transpose-convert W [k][d] fp32 -> Wt [d][k] bf16 (32x32 tiles) ----
__global__ __launch_bounds__(256) void mha_tW(const float* __restrict__ Wq, const float* __restrict__ Wk,
                                              const float* __restrict__ Wv,
                                              unsigned short* __restrict__ Wqt, unsigned short* __restrict__ Wkt,
                                              unsigned short* __restrict__ Wvt) {
  const float* W = (blockIdx.z == 0) ? Wq : (blockIdx.z == 1) ? Wk : Wv;
  unsigned short* Wt = (blockIdx.z == 0) ? Wqt : (blockIdx.z == 1) ? Wkt : Wvt;
  __shared__ float tile[32][33];
  int d0 = blockIdx.x * 32, k0 = blockIdx.y * 32;
  int t = threadIdx.x, r = t >> 3, c4 = (t & 7) * 4;
  float4 v = *(const float4*)(W + (size_t)(k0 + r) * DD + d0 + c4);
  tile[r][c4] = v.x; tile[r][c4 + 1] = v.y; tile[r][c4 + 2] = v.z; tile[r][c4 + 3] = v.w;
  __syncthreads();
  union { unsigned short s[4]; uint2 v; } u;
  u.s[0] = f2bf(tile[c4][r]);     u.s[1] = f2bf(tile[c4 + 1][r]);
  u.s[2] = f2bf(tile[c4 + 2][r]); u.s[3] = f2bf(tile[c4 + 3][r]);
  *(uint2*)(Wt + (size_t)(d0 + r) * DD + k0 + c4) = u.v;
}

// ---- transpose V (bf16) [b][n][d] -> Vt [b][d][n] (32x32 tiles) ----
__global__ __launch_bounds__(256) void mha_tV(const unsigned short* __restrict__ Vr,
                                              unsigned short* __restrict__ Vt) {
  int b = blockIdx.z;
  int d0 = blockIdx.x * 32, n0 = blockIdx.y * 32;
  __shared__ unsigned short tile[32][34];
  int t = threadIdx.x, r = t >> 3, c4 = (t & 7) * 4;
  union { uint2 v; unsigned short s[4]; } u;
  u.v = *(const uint2*)(Vr + ((size_t)b * NN + n0 + r) * DD + d0 + c4);
  tile[r][c4] = u.s[0]; tile[r][c4 + 1] = u.s[1]; tile[r][c4 + 2] = u.s[2]; tile[r][c4 + 3] = u.s[3];
  __syncthreads();
  union { unsigned short s[4]; uint2 v; } o;
  o.s[0] = tile[c4][r]; o.s[1] = tile[c4 + 1][r]; o.s[2] = tile[c4 + 2][r]; o.s[3] = tile[c4 + 3][r];
  *(uint2*)(Vt + ((size_t)b * DD + d0 + r) * NN + n0 + c4) = o.v;
}

// ---- GEMM staging: 128 rows x 32-k, seg-swizzled on the GLOBAL side; LDS lane-linear ----
// logical k-chunk l of row r is stored at physical chunk (l + (r>>1)) & 3 of that row.
__device__ __forceinline__ void stage_tile_async(const unsigned short* __restrict__ g, int ld,
                                                 unsigned short* s, int t) {
#pragma unroll
  for (int h = 0; h < 2; ++h) {
    int c = t + h * 256;            // chunk 0..511 (128 rows x 4 chunks)
    int r = c >> 2, p = c & 3;
    int seg = (p - (r >> 1)) & 3;
    ld_lds16(g + (size_t)r * ld + seg * 8, s + c * 8);
  }
}

__device__ __forceinline__ void mfma_step(const unsigned short* As, const unsigned short* Bs,
                                          int wr, int wc, int quad, int lr, floatx4 acc[4][4]) {
  short8 a[4], b[4];
#pragma unroll
  for (int i = 0; i < 4; ++i) {
    int ra = wr * 64 + i * 16 + lr;
    int rb = wc * 64 + i * 16 + lr;
    a[i] = *(const short8*)(As + ra * 32 + ((quad + (ra >> 1)) & 3) * 8);
    b[i] = *(const short8*)(Bs + rb * 32 + ((quad + (rb >> 1)) & 3) * 8);
  }
#pragma unroll
  for (int i = 0; i < 4; ++i)
#pragma unroll
    for (int j = 0; j < 4; ++j)
      acc[i][j] = __builtin_amdgcn_mfma_f32_16x16x32_bf16(a[i], b[j], acc[i][j], 0, 0, 0);
}

// ---- QKV projection: C[m][d] = sum_k Hb[m][k] * Wt[d][k], bf16 out ----
__global__ __launch_bounds__(256) void mha_proj(const unsigned short* __restrict__ Hb,
                                                const unsigned short* __restrict__ Wqt,
                                                const unsigned short* __restrict__ Wkt,
                                                const unsigned short* __restrict__ Wvt,
                                                unsigned short* __restrict__ Qb,
                                                unsigned short* __restrict__ Kb,
                                                unsigned short* __restrict__ Vr) {
  const unsigned short* Wt = (blockIdx.z == 0) ? Wqt : (blockIdx.z == 1) ? Wkt : Wvt;
  unsigned short* dst = (blockIdx.z == 0) ? Qb : (blockIdx.z == 1) ? Kb : Vr;
  __shared__ unsigned short As[128 * 32], Bs[128 * 32];
  int t = threadIdx.x, wave = t >> 6, lane = t & 63, quad = lane >> 4, lr = lane & 15;
  int wr = wave >> 1, wc = wave & 1;
  int m0 = blockIdx.y * 128, n0 = blockIdx.x * 128;
  floatx4 acc[4][4] = {};
  for (int k0 = 0; k0 < DD; k0 += 32) {
    __syncthreads();
    stage_tile_async(Hb + (size_t)m0 * DD + k0, DD, As, t);
    stage_tile_async(Wt + (size_t)n0 * DD + k0, DD, Bs, t);
    __syncthreads();
    mfma_step(As, Bs, wr, wc, quad, lr, acc);
  }
#pragma unroll
  for (int i = 0; i < 4; ++i)
#pragma unroll
    for (int j = 0; j < 4; ++j)
#pragma unroll
      for (int r = 0; r < 4; ++r) {
        int row = m0 + wr * 64 + i * 16 + quad * 4 + r;
        int col = n0 + wc * 64 + j * 16 + lr;
        dst[(size_t)row * DD + col] = f2bf(acc[i][j][r]);
      }
}

// ---- scores: E = exp(scale*Q.K^T + bm - 16) written IN-PLACE over bm; l = row sums ----
// bm tile (128x128 bf16 = 32KB) is DMA'd into LDS during the K-loop, so the epilogue
// has no global-load latency chain. Row-rotated chunk placement avoids bank conflicts.
__global__ __launch_bounds__(256) void mha_scores(const unsigned short* __restrict__ Qb,
                                                  const unsigned short* __restrict__ Kb,
                                                  unsigned short* __restrict__ bmE,
                                                  float* __restrict__ l) {
  __shared__ unsigned short As[128 * 32], Bs[128 * 32], Bm[128 * 128];
  int b = blockIdx.z;
  int i0 = blockIdx.y * 128;
  int j0 = blockIdx.x * 128;
  int t = threadIdx.x, wave = t >> 6, lane = t & 63, quad = lane >> 4, lr = lane & 15;
  int wr = wave >> 1, wc = wave & 1;
  const unsigned short* Q = Qb + (size_t)b * NN * DD;
  const unsigned short* K = Kb + (size_t)b * NN * DD;
  unsigned short* bm = bmE + (size_t)b * NN * NN;
  const float scale = 0.04419417382415922f;  // 1/sqrt(512)

  floatx4 acc[4][4] = {};
  for (int kidx = 0; kidx < 16; ++kidx) {
    int k0 = kidx * 32;
    __syncthreads();
    stage_tile_async(Q + (size_t)i0 * DD + k0, DD, As, t);
    stage_tile_async(K + (size_t)j0 * DD + k0, DD, Bs, t);
    if (kidx < 8) {
      // bm tile: 2048 16B-chunks; LDS chunk (row*16 + phys) holds global k-chunk ((phys-row)&15)
      int c = kidx * 256 + t;
      int row = c >> 4, phys = c & 15;
      int s = (phys - row) & 15;
      ld_lds16(bm + (size_t)(i0 + row) * NN + j0 + s * 8, Bm + c * 8);
    }
    __syncthreads();
    mfma_step(As, Bs, wr, wc, quad, lr, acc);
  }

  float rs[4][4] = {};  // rowsum partials [row-tile][reg]
#pragma unroll
  for (int i = 0; i < 4; ++i) {
#pragma unroll
    for (int j = 0; j < 4; ++j) {
#pragma unroll
      for (int r = 0; r < 4; ++r) {
        int row_l = wr * 64 + i * 16 + quad * 4 + r;
        int col_l = wc * 64 + j * 16 + lr;
        int sseg = col_l >> 3;
        float bi = bf2f(Bm[(row_l * 16 + ((sseg + row_l) & 15)) * 8 + (col_l & 7)]);
        float sv = acc[i][j][r] * scale + bi - 16.0f;  // masked: bi=-inf -> e=0, no branch
        float e = __expf(sv);
        unsigned short eb = f2bf(e);
        __builtin_nontemporal_store(eb, &bm[(size_t)(i0 + row_l) * NN + j0 + col_l]);
        rs[i][r] += bf2f(eb);  // sum the ROUNDED value so PV's sum matches l exactly
      }
    }
  }
  // reduce row sums across the 16 lanes of each quad-group, then atomic to global
#pragma unroll
  for (int i = 0; i < 4; ++i)
#pragma unroll
    for (int r = 0; r < 4; ++r) {
      float v = rs[i][r];
      v += __shfl_xor(v, 1);
      v += __shfl_xor(v, 2);
      v += __shfl_xor(v, 4);
      v += __shfl_xor(v, 8);
      if (lr == 0) {
        int row = i0 + wr * 64 + i * 16 + quad * 4 + r;
        atomicAdd(&l[b * NN + row], v);
      }
    }
}

// ---- PV: out[i][d] = (sum_j E[i][j] * Vt[d][j]) / l[i], fp32 out ----
__global__ __launch_bounds__(256) void mha_pv(const unsigned short* __restrict__ E,
                                              const unsigned short* __restrict__ Vt,
                                              const float* __restrict__ l,
                                              float* __restrict__ out) {
  int b = blockIdx.z;
  int i0 = blockIdx.y * 128;
  int c0 = blockIdx.x * 128;
  __shared__ unsigned short As[128 * 32], Bs[128 * 32];
  int t = threadIdx.x, wave = t >> 6, lane = t & 63, quad = lane >> 4, lr = lane & 15;
  int wr = wave >> 1, wc = wave & 1;
  const unsigned short* Eb = E + (size_t)b * NN * NN;
  const unsigned short* Vb = Vt + (size_t)b * DD * NN;
  floatx4 acc[4][4] = {};
  for (int k0 = 0; k0 < NN; k0 += 32) {
    __syncthreads();
    stage_tile_async(Eb + (size_t)i0 * NN + k0, NN, As, t);
    stage_tile_async(Vb + (size_t)c0 * NN + k0, NN, Bs, t);
    __syncthreads();
    mfma_step(As, Bs, wr, wc, quad, lr, acc);
  }
#pragma unroll
  for (int i = 0; i < 4; ++i)
#pragma unroll
    for (int r = 0; r < 4; ++r) {
      int row = i0 + wr * 64 + i * 16 + quad * 4 + r;
      float linv = 1.0f / l[b * NN + row];
#pragma unroll
      for (int j = 0; j < 4; ++j) {
        int col = c0 + wc * 64 + j * 16 + lr;
        __builtin_nontemporal_store(acc[i][j][r] * linv,
                                    &out[((size_t)b * NN + row) * DD + col]);
      }
    }
}

extern "C" void kernel_launch(void* const* d_in, const int* in_sizes, int n_in,
                              void* d_out, int out_size, void* d_ws, size_t ws_size,
                              hipStream_t stream) {
  const float* H = (const float*)d_in[0];
  const float* bias = (const float*)d_in[1];
  const int* mask = (const int*)d_in[2];
  const float* Wq = (const float*)d_in[3];
  const float* Wk = (const float*)d_in[4];
  const float* Wv = (const float*)d_in[5];
  float* out = (float*)d_out;
  char* ws = (char*)d_ws;

  const size_t SZ_QKV = (size_t)NB * NN * DD * 2;  // 16 MB (bf16)
  const size_t SZ_W = (size_t)DD * DD * 2;          // 512 KB
  // Persistent region (48 MB + 64 KB)
  unsigned short* Qb = (unsigned short*)(ws);
  unsigned short* Kb = (unsigned short*)(ws + SZ_QKV);
  unsigned short* Vt = (unsigned short*)(ws + 2 * SZ_QKV);
  float* l = (float*)(ws + 3 * SZ_QKV);
  // Aliased region (67 MB): bmE overlays [Hb, Wt x3, Vr], all dead before mha_prep runs.
  // mha_scores then overwrites bm with E in-place (each block's bm tile is fully staged
  // to LDS before any E store). Total ws ~= 115 MB.
  char* base2 = ws + 3 * SZ_QKV + (((size_t)NB * NN * 4 + 255) & ~255ULL);
  unsigned short* bmE = (unsigned short*)(base2);
  unsigned short* Hb = (unsigned short*)(base2);
  unsigned short* Wqt = (unsigned short*)(base2 + SZ_QKV);
  unsigned short* Wkt = (unsigned short*)(base2 + SZ_QKV + SZ_W);
  unsigned short* Wvt = (unsigned short*)(base2 + SZ_QKV + 2 * SZ_W);
  unsigned short* Vr = (unsigned short*)(base2 + SZ_QKV + 3 * SZ_W);

  (void)hipMemsetAsync(l, 0, (size_t)NB * NN * 4, stream);
  mha_cvtH<<<dim3((NB * NN * DD / 8) / 256), 256, 0, stream>>>(H, Hb, NB * NN * DD / 8);
  mha_tW<<<dim3(DD / 32, DD / 32, 3), 256, 0, stream>>>(Wq, Wk, Wv, Wqt, Wkt, Wvt);
  mha_proj<<<dim3(DD / 128, NB * NN / 128, 3), 256, 0, stream>>>(Hb, Wqt, Wkt, Wvt, Qb, Kb, Vr);
  mha_tV<<<dim3(DD / 32, NN / 32, NB), 256, 0, stream>>>(Vr, Vt);
  mha_prep<<<dim3((NB * NN * NN / 4) / 256), 256, 0, stream>>>((const floatx4*)bias,
                                                               (const intx4*)mask, (ushortx4*)bmE);
  mha_scores<<<dim3(NN / 128, NN / 128, NB), 256, 0, stream>>>(Qb, Kb, bmE, l);
  mha_pv<<<dim3(DD / 128, NN / 128, NB), 256, 0, stream>>>(bmE, Vt, l, out);
}